// Round 4
// baseline (386.638 us; speedup 1.0000x reference)
//
#include <hip/hip_runtime.h>
#include <math.h>

#define SQ 2048      // seq len
#define DE 512       // d_embedding
#define DH 64        // d_head
#define CW 128       // half-window
#define W2 256       // window width
#define NH 8         // heads
#define NQ 8         // queries per block (R3: was 4; halves per-dispatch weight re-reads)
#define UW (W2 + NQ - 1)  // union window width = 263
#define NT 512       // threads per block
#define NW 8         // waves per block
#define NB (SQ / NQ) // 256 blocks

// XCD-chunk swizzle (bijective for 256 blocks, 8 XCDs): dispatch d -> XCD d%8
// round-robin; give XCD k the contiguous row band [k*256, (k+1)*256).
__device__ __forceinline__ int swz_block(int b) {
  return ((b & 7) << 5) | (b >> 3);
}

// prep: packed-float4 weight layouts.
// WT4[h][e/4][c][u] (u=e%4): lane c loads float4 covering 4 consecutive e.
// VT4[h][c/4][e][u] (u=c%4): lane e loads float4 covering 4 consecutive c.
__global__ __launch_bounds__(256) void prep_kernel(
    const float* __restrict__ Wq, const float* __restrict__ Wk,
    const float* __restrict__ Wvd, const float* __restrict__ Wvu,
    float* __restrict__ WT4q, float* __restrict__ WT4k, float* __restrict__ WT4v,
    float* __restrict__ VT4) {
  int i = blockIdx.x * 256 + threadIdx.x;
  if (i < NH * DE * DH) {
    int c = i & 63;
    int e = (i >> 6) & 511;
    int h = i >> 15;
    int src = (h * DH + c) * DE + e;
    int w4i = ((h * 128 + (e >> 2)) * 64 + c) * 4 + (e & 3);
    WT4q[w4i] = Wq[src];
    WT4k[w4i] = Wk[src];
    WT4v[w4i] = Wvd[src];
    int v4i = ((h * 16 + (c >> 2)) * 512 + e) * 4 + (c & 3);
    VT4[v4i] = Wvu[(h * DE + e) * DH + c];
  }
}

// qkv0: x -> cur copy + q/kT/v for head 0 (float4 weight loads)
__global__ __launch_bounds__(NT) void qkv0_kernel(
    const float* __restrict__ x,
    const float4* __restrict__ Wq4, const float4* __restrict__ Wk4,
    const float4* __restrict__ Wv4, float* __restrict__ cur,
    float* __restrict__ q, float* __restrict__ kT, float* __restrict__ v) {
  __shared__ float xL[NQ][DE];          // 16 KB
  __shared__ float qP[NW][3][NQ][DH];   // 48 KB
  int tid = threadIdx.x, lane = tid & 63, wv = tid >> 6;
  int j0 = swz_block(blockIdx.x) * NQ;

  const float4* xs = (const float4*)(x + (size_t)j0 * DE);
  float4* cs = (float4*)(cur + (size_t)j0 * DE);
#pragma unroll
  for (int t = 0; t < NQ * DE / 4 / NT; t++) {  // 2 iterations
    float4 xv = xs[tid + NT * t];
    ((float4*)xL)[tid + NT * t] = xv;
    cs[tid + NT * t] = xv;
  }
  __syncthreads();

  float aq[NQ] = {0, 0, 0, 0, 0, 0, 0, 0};
  float ak[NQ] = {0, 0, 0, 0, 0, 0, 0, 0};
  float av[NQ] = {0, 0, 0, 0, 0, 0, 0, 0};
  int e0 = wv * 64;
#pragma unroll
  for (int i4 = 0; i4 < 16; i4++) {
    int widx = (wv * 16 + i4) * 64 + lane;
    float4 wq4 = Wq4[widx];
    float4 wk4 = Wk4[widx];
    float4 wv4 = Wv4[widx];
#pragma unroll
    for (int r = 0; r < NQ; r++) {
      float4 xr = ((const float4*)&xL[r][e0])[i4];
      aq[r] += xr.x * wq4.x + xr.y * wq4.y + xr.z * wq4.z + xr.w * wq4.w;
      ak[r] += xr.x * wk4.x + xr.y * wk4.y + xr.z * wk4.z + xr.w * wk4.w;
      av[r] += xr.x * wv4.x + xr.y * wv4.y + xr.z * wv4.z + xr.w * wv4.w;
    }
  }
#pragma unroll
  for (int r = 0; r < NQ; r++) {
    qP[wv][0][r][lane] = aq[r];
    qP[wv][1][r][lane] = ak[r];
    qP[wv][2][r][lane] = av[r];
  }
  __syncthreads();
  for (int i = tid; i < 3 * NQ * DH; i += NT) {  // 1536 outputs, 3 iters
    int o = i >> 9;
    int rem = i & 511;
    int r = rem >> 6, c = rem & 63;
    float s = 0;
#pragma unroll
    for (int w = 0; w < NW; w++) s += qP[w][o][r][c];
    if (o == 0) q[(size_t)(j0 + r) * DH + c] = s;
    else if (o == 1) kT[(size_t)c * SQ + (j0 + r)] = s;
    else v[(size_t)(j0 + r) * DH + c] = s;
  }
}

// fused: attn(head h) [+ qkv(head h+1)]
// flags bit0: last head -> out = cur/8 ; bit1: compute next-head qkv
__global__ __launch_bounds__(NT) void fused_kernel(
    float* __restrict__ cur,
    const float* __restrict__ q, const float* __restrict__ kT,
    const float* __restrict__ v, const float4* __restrict__ VT4h,
    const float4* __restrict__ Wq4n, const float4* __restrict__ Wk4n,
    const float4* __restrict__ Wv4n,
    float* __restrict__ qn, float* __restrict__ kTn, float* __restrict__ vn,
    float* __restrict__ out, int flags) {
  // LDS aliasing: qP (48KB, live only in P7, first write after the post-P6
  // barrier) overlays sL+pL (24KB, dead after the dL-reduce barrier).
  __shared__ union SMem {
    struct { float sL[NQ][W2]; float pL[NW][NQ][DH]; } a;
    float qP[NW][3][NQ][DH];
  } sm;
  __shared__ float dL[NQ][DH];
  __shared__ float yL[NQ][DE];

  int tid = threadIdx.x, lane = tid & 63, wv = tid >> 6;
  int j0 = swz_block(blockIdx.x) * NQ;

  // P1: scores. q rows read directly from global with wave-uniform indices
  // (compiler emits scalar loads; q is L2-warm, written last dispatch).
  // No P0 staging phase / barrier needed.
  if (wv < 5) {                    // waves 0-4 cover goff 0..319 >= UW=263
    int goff = wv * 64 + lane;
    int g = j0 - CW + goff;
    bool valid = (g >= 0 && g < SQ);
    int gc = valid ? g : 0;
    float acc[NQ] = {0, 0, 0, 0, 0, 0, 0, 0};
#pragma unroll
    for (int d8 = 0; d8 < 8; d8++) {
      float kc[8];
#pragma unroll
      for (int u = 0; u < 8; u++) kc[u] = kT[(size_t)(d8 * 8 + u) * SQ + gc];
#pragma unroll
      for (int r = 0; r < NQ; r++) {
        const float4* q4 = (const float4*)(q + (size_t)(j0 + r) * DH);
        float4 q0 = q4[2 * d8];
        float4 q1 = q4[2 * d8 + 1];
        acc[r] += q0.x * kc[0] + q0.y * kc[1] + q0.z * kc[2] + q0.w * kc[3] +
                  q1.x * kc[4] + q1.y * kc[5] + q1.z * kc[6] + q1.w * kc[7];
      }
    }
#pragma unroll
    for (int r = 0; r < NQ; r++) {
      int p = goff - r;
      if (p >= 0 && p < W2) sm.a.sL[r][p] = valid ? acc[r] * 0.125f : -INFINITY;
    }
  }
  __syncthreads();

  // v-prefetch (chunk 0 of P3): independent of softmax; latency hides under P2.
  int gbeg = 33 * wv;
  float vpf[16];
#pragma unroll
  for (int i = 0; i < 16; i++) {
    int goff = gbeg + i;
    int g = j0 - CW + goff;
    int gc = g < 0 ? 0 : (g >= SQ ? SQ - 1 : g);
    vpf[i] = v[(size_t)gc * DH + lane];
  }

  // P2: softmax; 8 waves, one row each (NQ == NW)
  {
    int r = wv;
    float m = -INFINITY;
#pragma unroll
    for (int t = 0; t < 4; t++) m = fmaxf(m, sm.a.sL[r][lane + 64 * t]);
#pragma unroll
    for (int off = 32; off; off >>= 1) m = fmaxf(m, __shfl_xor(m, off));
    float ex[4], ss = 0;
#pragma unroll
    for (int t = 0; t < 4; t++) {
      ex[t] = __expf(sm.a.sL[r][lane + 64 * t] - m);
      ss += ex[t];
    }
#pragma unroll
    for (int off = 32; off; off >>= 1) ss += __shfl_xor(ss, off);
    float inv = 1.0f / ss;
#pragma unroll
    for (int t = 0; t < 4; t++) sm.a.sL[r][lane + 64 * t] = ex[t] * inv;
  }
  __syncthreads();

  // P3: PV. Chunk 0 uses prefetched v; chunks 1-2 (17 values) load inline.
  {
    float dacc[NQ] = {0, 0, 0, 0, 0, 0, 0, 0};
#pragma unroll
    for (int i = 0; i < 16; i++) {
      int goff = gbeg + i;
#pragma unroll
      for (int r = 0; r < NQ; r++) {
        int p = goff - r;
        float w = (goff < UW && p >= 0 && p < W2) ? sm.a.sL[r][p & 255] : 0.0f;
        dacc[r] += w * vpf[i];
      }
    }
    {
      float vcv[17];
#pragma unroll
      for (int i = 0; i < 17; i++) {
        int goff = gbeg + 16 + i;
        int g = j0 - CW + goff;
        int gc = g < 0 ? 0 : (g >= SQ ? SQ - 1 : g);
        vcv[i] = v[(size_t)gc * DH + lane];
      }
#pragma unroll
      for (int i = 0; i < 17; i++) {
        int goff = gbeg + 16 + i;
        bool act = goff < UW;
#pragma unroll
        for (int r = 0; r < NQ; r++) {
          int p = goff - r;
          float w = (act && p >= 0 && p < W2) ? sm.a.sL[r][p & 255] : 0.0f;
          dacc[r] += w * vcv[i];
        }
      }
    }
#pragma unroll
    for (int r = 0; r < NQ; r++) sm.a.pL[wv][r][lane] = dacc[r];
  }
  __syncthreads();
  {  // dL reduce: 512 threads == NQ*DH, one element each
    int r = tid >> 6, c = tid & 63;
    float s = 0;
#pragma unroll
    for (int w = 0; w < NW; w++) s += sm.a.pL[w][r][c];
    dL[r][c] = s;
  }
  __syncthreads();

  // P5: upproj with float4 VT loads; thread owns e = tid
  float c8[8];
  {
    int e = tid;
    float cr[NQ];
#pragma unroll
    for (int r = 0; r < NQ; r++) cr[r] = cur[(size_t)(j0 + r) * DE + e];
    {
      size_t jrow = (size_t)(j0 + wv) * DE;
#pragma unroll
      for (int t = 0; t < 8; t++) c8[t] = cur[jrow + lane + 64 * t];
    }
    float acc[NQ] = {0, 0, 0, 0, 0, 0, 0, 0};
#pragma unroll
    for (int c4 = 0; c4 < 16; c4++) {
      float4 wc4 = VT4h[c4 * 512 + e];
#pragma unroll
      for (int r = 0; r < NQ; r++) {
        float4 df = ((const float4*)dL[r])[c4];
        acc[r] += df.x * wc4.x + df.y * wc4.y + df.z * wc4.z + df.w * wc4.w;
      }
    }
#pragma unroll
    for (int r = 0; r < NQ; r++) yL[r][e] = cr[r] + acc[r];
  }
  __syncthreads();

  // P6: renorm + residual; 8 waves, one row each
  {
    int r = wv;
    size_t jrow = (size_t)(j0 + r) * DE;
    float s = 0;
#pragma unroll
    for (int t = 0; t < 8; t++) s += yL[r][lane + 64 * t];
#pragma unroll
    for (int off = 32; off; off >>= 1) s += __shfl_xor(s, off);
    float inv_m1 = 512.0f / s;
    float y2[8], s2 = 0, s2q = 0;
#pragma unroll
    for (int t = 0; t < 8; t++) {
      y2[t] = yL[r][lane + 64 * t] * inv_m1;
      s2 += y2[t];
      s2q += y2[t] * y2[t];
    }
#pragma unroll
    for (int off = 32; off; off >>= 1) {
      s2 += __shfl_xor(s2, off);
      s2q += __shfl_xor(s2q, off);
    }
    float m2 = s2 * (1.0f / 512.0f);
    float var = (s2q - 512.0f * m2 * m2) * (1.0f / 511.0f);
    float isd = 1.0f / sqrtf(var);
#pragma unroll
    for (int t = 0; t < 8; t++) {
      int e = lane + 64 * t;
      float o = (y2[t] - m2) * isd + m2;
      float nc = c8[t] + o;
      cur[jrow + e] = nc;
      yL[r][e] = nc;
      if (flags & 1) out[jrow + e] = nc * (1.0f / NH);
    }
  }
  __syncthreads();

  // P7: next-head qkv with float4 weight loads; wave e-slice.
  // (qP aliases sL/pL -- all their reads are ordered before this barrier.)
  if (flags & 2) {
    float aq[NQ] = {0, 0, 0, 0, 0, 0, 0, 0};
    float ak[NQ] = {0, 0, 0, 0, 0, 0, 0, 0};
    float av[NQ] = {0, 0, 0, 0, 0, 0, 0, 0};
    int e0 = wv * 64;
#pragma unroll
    for (int i4 = 0; i4 < 16; i4++) {
      int widx = (wv * 16 + i4) * 64 + lane;
      float4 wq4 = Wq4n[widx];
      float4 wk4 = Wk4n[widx];
      float4 wv4 = Wv4n[widx];
#pragma unroll
      for (int r = 0; r < NQ; r++) {
        float4 xr = ((const float4*)&yL[r][e0])[i4];
        aq[r] += xr.x * wq4.x + xr.y * wq4.y + xr.z * wq4.z + xr.w * wq4.w;
        ak[r] += xr.x * wk4.x + xr.y * wk4.y + xr.z * wk4.z + xr.w * wk4.w;
        av[r] += xr.x * wv4.x + xr.y * wv4.y + xr.z * wv4.z + xr.w * wv4.w;
      }
    }
#pragma unroll
    for (int r = 0; r < NQ; r++) {
      sm.qP[wv][0][r][lane] = aq[r];
      sm.qP[wv][1][r][lane] = ak[r];
      sm.qP[wv][2][r][lane] = av[r];
    }
    __syncthreads();
    for (int i = tid; i < 3 * NQ * DH; i += NT) {  // 1536 outputs, 3 iters
      int o = i >> 9;
      int rem = i & 511;
      int r = rem >> 6, c = rem & 63;
      float s = 0;
#pragma unroll
      for (int w = 0; w < NW; w++) s += sm.qP[w][o][r][c];
      if (o == 0) qn[(size_t)(j0 + r) * DH + c] = s;
      else if (o == 1) kTn[(size_t)c * SQ + (j0 + r)] = s;
      else vn[(size_t)(j0 + r) * DH + c] = s;
    }
  }
}

extern "C" void kernel_launch(void* const* d_in, const int* in_sizes, int n_in,
                              void* d_out, int out_size, void* d_ws, size_t ws_size,
                              hipStream_t stream) {
  const float* x   = (const float*)d_in[0];
  const float* Wq  = (const float*)d_in[1];
  const float* Wk  = (const float*)d_in[2];
  const float* Wvd = (const float*)d_in[3];
  const float* Wvu = (const float*)d_in[4];
  float* out = (float*)d_out;

  float* ws  = (float*)d_ws;
  float* cur = ws;                    // SQ*DE
  float* qA  = cur + SQ * DE;         // SQ*DH each; k in kT layout [DH][SQ]
  float* kA  = qA + SQ * DH;
  float* vA  = kA + SQ * DH;
  float* qB  = vA + SQ * DH;
  float* kB  = qB + SQ * DH;
  float* vB  = kB + SQ * DH;
  float* WTq = vB + SQ * DH;          // NH*DE*DH each (packed float4 layout)
  float* WTk = WTq + NH * DE * DH;
  float* WTv = WTk + NH * DE * DH;
  float* VT  = WTv + NH * DE * DH;    // NH*DH*DE (packed float4 layout)

  prep_kernel<<<NH * DE * DH / 256, 256, 0, stream>>>(Wq, Wk, Wvd, Wvu,
                                                      WTq, WTk, WTv, VT);
  qkv0_kernel<<<NB, NT, 0, stream>>>(
      x, (const float4*)WTq, (const float4*)WTk, (const float4*)WTv,
      cur, qA, kA, vA);

  for (int h = 0; h < NH; h++) {
    const float* qi = (h & 1) ? qB : qA;
    const float* ki = (h & 1) ? kB : kA;
    const float* vi = (h & 1) ? vB : vA;
    float* qo = (h & 1) ? qA : qB;
    float* ko = (h & 1) ? kA : kB;
    float* vo = (h & 1) ? vA : vB;
    const size_t won = (size_t)(h + 1 < NH ? h + 1 : 0) * DE * DH / 4;
    int flags = (h == NH - 1 ? 1 : 0) | (h < NH - 1 ? 2 : 0);
    fused_kernel<<<NB, NT, 0, stream>>>(
        cur, qi, ki, vi, (const float4*)VT + (size_t)h * DH * DE / 4,
        (const float4*)WTq + won, (const float4*)WTk + won,
        (const float4*)WTv + won, qo, ko, vo, out, flags);
  }
}

// Round 6
// 315.658 us; speedup vs baseline: 1.2249x; 1.2249x over previous
//
#include <hip/hip_runtime.h>
#include <hip/hip_cooperative_groups.h>
#include <math.h>

namespace cg = cooperative_groups;

#define SQ 2048      // seq len
#define DE 512       // d_embedding
#define DH 64        // d_head
#define CW 128       // half-window
#define W2 256       // window width
#define NH 8         // heads
#define NQ 4         // queries per block
#define UW (W2 + NQ - 1)  // union window width = 259
#define NT 512       // threads per block
#define NW 8         // waves per block
#define NB (SQ / NQ) // 512 blocks = 2 per CU (cooperative-resident)

// XCD-chunk swizzle (bijective for 512 blocks, 8 XCDs).
__device__ __forceinline__ int swz_block(int b) {
  return ((b & 7) << 6) | (b >> 3);
}

// prep: packed-float4 weight layouts.
__global__ __launch_bounds__(256) void prep_kernel(
    const float* __restrict__ Wq, const float* __restrict__ Wk,
    const float* __restrict__ Wvd, const float* __restrict__ Wvu,
    float* __restrict__ WT4q, float* __restrict__ WT4k, float* __restrict__ WT4v,
    float* __restrict__ VT4) {
  int i = blockIdx.x * 256 + threadIdx.x;
  if (i < NH * DE * DH) {
    int c = i & 63;
    int e = (i >> 6) & 511;
    int h = i >> 15;
    int src = (h * DH + c) * DE + e;
    int w4i = ((h * 128 + (e >> 2)) * 64 + c) * 4 + (e & 3);
    WT4q[w4i] = Wq[src];
    WT4k[w4i] = Wk[src];
    WT4v[w4i] = Wvd[src];
    int v4i = ((h * 16 + (c >> 2)) * 512 + e) * 4 + (c & 3);
    VT4[v4i] = Wvu[(h * DE + e) * DH + c];
  }
}

// ---------------- persistent cooperative path ----------------
// All 8 heads in one launch, grid.sync() between heads. Block-local state in
// LDS across heads: yL = cur rows, qL = q rows. Only kT/v go through global.
// LDS = 22KB/block so 2 blocks/CU fits even a 64KB-based occupancy account
// (R4 fail: 34KB x 2 = 69.6KB > 64KB -> occupancy 1 -> coop launch rejected).
__global__ __launch_bounds__(NT, 4) void persist_kernel(
    const float* __restrict__ x,
    const float4* __restrict__ WTq4, const float4* __restrict__ WTk4,
    const float4* __restrict__ WTv4, const float4* __restrict__ VT4,
    float* __restrict__ kA, float* __restrict__ vA,
    float* __restrict__ kB, float* __restrict__ vB,
    float* __restrict__ out) {
  cg::grid_group grid = cg::this_grid();

  // qH (12KB, live only inside QKV) overlays sL+pL (12KB, dead by then).
  __shared__ union SMem {
    struct { float sL[NQ][W2]; float pL[NW][NQ][DH]; } a;  // 4KB + 8KB
    float qH[4][3][NQ][DH];                                 // 12KB
  } sm;
  __shared__ float yL[NQ][DE];   // 8 KB: block's cur rows
  __shared__ float qL[NQ][DH];   // 1 KB: block's q rows
  __shared__ float dL[NQ][DH];   // 1 KB

  int tid = threadIdx.x, lane = tid & 63, wv = tid >> 6;
  int j0 = swz_block(blockIdx.x) * NQ;

  // ---- stage x rows into yL (cur never materialized in global) ----
  ((float4*)yL)[tid] = ((const float4*)(x + (size_t)j0 * DE))[tid];
  __syncthreads();

  // ---- QKV for head hn from yL -> qL (LDS) + kTn/vn (global) ----
  // Two-round cross-wave reduce through 12KB qH (not 24KB full-NW array).
  auto QKV = [&](int hn, float* kTn, float* vn) {
    const float4* Wq4n = WTq4 + (size_t)hn * (DE * DH / 4);
    const float4* Wk4n = WTk4 + (size_t)hn * (DE * DH / 4);
    const float4* Wv4n = WTv4 + (size_t)hn * (DE * DH / 4);
    float aq[NQ] = {0, 0, 0, 0}, ak[NQ] = {0, 0, 0, 0}, av[NQ] = {0, 0, 0, 0};
    int e0 = wv * 64;
#pragma unroll
    for (int i4 = 0; i4 < 16; i4++) {
      int widx = (wv * 16 + i4) * 64 + lane;
      float4 wq4 = Wq4n[widx];
      float4 wk4 = Wk4n[widx];
      float4 wv4 = Wv4n[widx];
#pragma unroll
      for (int r = 0; r < NQ; r++) {
        float4 xr = ((const float4*)&yL[r][e0])[i4];
        aq[r] += xr.x * wq4.x + xr.y * wq4.y + xr.z * wq4.z + xr.w * wq4.w;
        ak[r] += xr.x * wk4.x + xr.y * wk4.y + xr.z * wk4.z + xr.w * wk4.w;
        av[r] += xr.x * wv4.x + xr.y * wv4.y + xr.z * wv4.z + xr.w * wv4.w;
      }
    }
    if (wv >= 4) {
#pragma unroll
      for (int r = 0; r < NQ; r++) {
        sm.qH[wv - 4][0][r][lane] = aq[r];
        sm.qH[wv - 4][1][r][lane] = ak[r];
        sm.qH[wv - 4][2][r][lane] = av[r];
      }
    }
    __syncthreads();
    if (wv < 4) {
#pragma unroll
      for (int r = 0; r < NQ; r++) {
        sm.qH[wv][0][r][lane] += aq[r];
        sm.qH[wv][1][r][lane] += ak[r];
        sm.qH[wv][2][r][lane] += av[r];
      }
    }
    __syncthreads();
    for (int i = tid; i < 3 * NQ * DH; i += NT) {
      int o = i >> 8;
      int rem = i & 255;
      int r = rem >> 6, c = rem & 63;
      float s = sm.qH[0][o][r][c] + sm.qH[1][o][r][c] +
                sm.qH[2][o][r][c] + sm.qH[3][o][r][c];
      if (o == 0) qL[r][c] = s;
      else if (o == 1) kTn[(size_t)c * SQ + (j0 + r)] = s;
      else vn[(size_t)(j0 + r) * DH + c] = s;
    }
    // no trailing __syncthreads: every call is followed by grid.sync()
  };

  QKV(0, kA, vA);
  grid.sync();

  for (int h = 0; h < NH; h++) {
    const float* kT = (h & 1) ? kB : kA;
    const float* v  = (h & 1) ? vB : vA;
    float* kTn = (h & 1) ? kA : kB;
    float* vn  = (h & 1) ? vA : vB;

    // P1: scores (waves 0-4 cover goff 0..319 >= UW); qL broadcast reads.
    if (wv < 5) {
      int goff = wv * 64 + lane;
      int g = j0 - CW + goff;
      bool valid = (g >= 0 && g < SQ);
      int gc = valid ? g : 0;
      float acc[NQ] = {0, 0, 0, 0};
#pragma unroll
      for (int d8 = 0; d8 < 8; d8++) {
        float kc[8];
#pragma unroll
        for (int u = 0; u < 8; u++) kc[u] = kT[(size_t)(d8 * 8 + u) * SQ + gc];
#pragma unroll
        for (int r = 0; r < NQ; r++) {
          float4 q0 = ((const float4*)qL[r])[2 * d8];
          float4 q1 = ((const float4*)qL[r])[2 * d8 + 1];
          acc[r] += q0.x * kc[0] + q0.y * kc[1] + q0.z * kc[2] + q0.w * kc[3] +
                    q1.x * kc[4] + q1.y * kc[5] + q1.z * kc[6] + q1.w * kc[7];
        }
      }
#pragma unroll
      for (int r = 0; r < NQ; r++) {
        int p = goff - r;
        if (p >= 0 && p < W2) sm.a.sL[r][p] = valid ? acc[r] * 0.125f : -INFINITY;
      }
    }
    __syncthreads();

    // P2: softmax, wave per row
    if (wv < NQ) {
      int r = wv;
      float m = -INFINITY;
#pragma unroll
      for (int t = 0; t < 4; t++) m = fmaxf(m, sm.a.sL[r][lane + 64 * t]);
#pragma unroll
      for (int off = 32; off; off >>= 1) m = fmaxf(m, __shfl_xor(m, off));
      float ex[4], ss = 0;
#pragma unroll
      for (int t = 0; t < 4; t++) {
        ex[t] = __expf(sm.a.sL[r][lane + 64 * t] - m);
        ss += ex[t];
      }
#pragma unroll
      for (int off = 32; off; off >>= 1) ss += __shfl_xor(ss, off);
      float inv = 1.0f / ss;
#pragma unroll
      for (int t = 0; t < 4; t++) sm.a.sL[r][lane + 64 * t] = ex[t] * inv;
    }
    __syncthreads();

    // P3: PV, 3 chunks of 11
    {
      float dacc[NQ] = {0, 0, 0, 0};
      int gbeg = 33 * wv;
#pragma unroll
      for (int ch = 0; ch < 3; ch++) {
        float vc[11];
#pragma unroll
        for (int i = 0; i < 11; i++) {
          int goff = gbeg + ch * 11 + i;
          int g = j0 - CW + goff;
          int gc = g < 0 ? 0 : (g >= SQ ? SQ - 1 : g);
          vc[i] = v[(size_t)gc * DH + lane];
        }
#pragma unroll
        for (int i = 0; i < 11; i++) {
          int goff = gbeg + ch * 11 + i;
          bool act = goff < UW;
#pragma unroll
          for (int r = 0; r < NQ; r++) {
            int p = goff - r;
            float w = (act && p >= 0 && p < W2) ? sm.a.sL[r][p & 255] : 0.0f;
            dacc[r] += w * vc[i];
          }
        }
      }
#pragma unroll
      for (int r = 0; r < NQ; r++) sm.a.pL[wv][r][lane] = dacc[r];
    }
    __syncthreads();
    if (tid < NQ * DH) {
      int r = tid >> 6, c = tid & 63;
      float s = 0;
#pragma unroll
      for (int w = 0; w < NW; w++) s += sm.a.pL[w][r][c];
      dL[r][c] = s;
    }
    __syncthreads();

    // P5: upproj; cur rows come from yL (LDS-carried).
    float c8[8];
    {
      int e = tid;
      float cr[NQ];
#pragma unroll
      for (int r = 0; r < NQ; r++) cr[r] = yL[r][e];
      if (wv < NQ) {
#pragma unroll
        for (int t = 0; t < 8; t++) c8[t] = yL[wv][lane + 64 * t];
      }
      __syncthreads();  // all yL reads complete before overwrite
      const float4* VT4h = VT4 + (size_t)h * (DH * DE / 4);
      float acc[NQ] = {0, 0, 0, 0};
#pragma unroll
      for (int c4 = 0; c4 < 16; c4++) {
        float4 wc4 = VT4h[c4 * 512 + e];
#pragma unroll
        for (int r = 0; r < NQ; r++) {
          float4 df = ((const float4*)dL[r])[c4];
          acc[r] += df.x * wc4.x + df.y * wc4.y + df.z * wc4.z + df.w * wc4.w;
        }
      }
#pragma unroll
      for (int r = 0; r < NQ; r++) yL[r][e] = cr[r] + acc[r];
    }
    __syncthreads();

    // P6: renorm + residual; wave per row; result stays in yL.
    if (wv < NQ) {
      int r = wv;
      float s = 0;
#pragma unroll
      for (int t = 0; t < 8; t++) s += yL[r][lane + 64 * t];
#pragma unroll
      for (int off = 32; off; off >>= 1) s += __shfl_xor(s, off);
      float inv_m1 = 512.0f / s;
      float y2[8], s2 = 0, s2q = 0;
#pragma unroll
      for (int t = 0; t < 8; t++) {
        y2[t] = yL[r][lane + 64 * t] * inv_m1;
        s2 += y2[t];
        s2q += y2[t] * y2[t];
      }
#pragma unroll
      for (int off = 32; off; off >>= 1) {
        s2 += __shfl_xor(s2, off);
        s2q += __shfl_xor(s2q, off);
      }
      float m2 = s2 * (1.0f / 512.0f);
      float var = (s2q - 512.0f * m2 * m2) * (1.0f / 511.0f);
      float isd = 1.0f / sqrtf(var);
#pragma unroll
      for (int t = 0; t < 8; t++) {
        int e = lane + 64 * t;
        float o = (y2[t] - m2) * isd + m2;
        float nc = c8[t] + o;
        yL[r][e] = nc;
        if (h == NH - 1) out[(size_t)(j0 + r) * DE + e] = nc * (1.0f / NH);
      }
    }
    __syncthreads();

    if (h < NH - 1) {
      QKV(h + 1, kTn, vn);
      grid.sync();
    }
  }
}

// ---------------- fallback dispatch path (R2, known-good 315us) ----------------
__global__ __launch_bounds__(NT) void qkv0_kernel(
    const float* __restrict__ x,
    const float4* __restrict__ Wq4, const float4* __restrict__ Wk4,
    const float4* __restrict__ Wv4, float* __restrict__ cur,
    float* __restrict__ q, float* __restrict__ kT, float* __restrict__ v) {
  __shared__ float xL[NQ][DE];
  __shared__ float qP[NW][3][NQ][DH];
  int tid = threadIdx.x, lane = tid & 63, wv = tid >> 6;
  int j0 = swz_block(blockIdx.x) * NQ;

  float4 xv = ((const float4*)(x + (size_t)j0 * DE))[tid];
  ((float4*)xL)[tid] = xv;
  ((float4*)(cur + (size_t)j0 * DE))[tid] = xv;
  __syncthreads();

  float aq[NQ] = {0, 0, 0, 0}, ak[NQ] = {0, 0, 0, 0}, av[NQ] = {0, 0, 0, 0};
  int e0 = wv * 64;
#pragma unroll
  for (int i4 = 0; i4 < 16; i4++) {
    int widx = (wv * 16 + i4) * 64 + lane;
    float4 wq4 = Wq4[widx];
    float4 wk4 = Wk4[widx];
    float4 wv4 = Wv4[widx];
#pragma unroll
    for (int r = 0; r < NQ; r++) {
      float4 xr = ((const float4*)&xL[r][e0])[i4];
      aq[r] += xr.x * wq4.x + xr.y * wq4.y + xr.z * wq4.z + xr.w * wq4.w;
      ak[r] += xr.x * wk4.x + xr.y * wk4.y + xr.z * wk4.z + xr.w * wk4.w;
      av[r] += xr.x * wv4.x + xr.y * wv4.y + xr.z * wv4.z + xr.w * wv4.w;
    }
  }
#pragma unroll
  for (int r = 0; r < NQ; r++) {
    qP[wv][0][r][lane] = aq[r];
    qP[wv][1][r][lane] = ak[r];
    qP[wv][2][r][lane] = av[r];
  }
  __syncthreads();
  for (int i = tid; i < 3 * NQ * DH; i += NT) {
    int o = i >> 8;
    int rem = i & 255;
    int r = rem >> 6, c = rem & 63;
    float s = 0;
#pragma unroll
    for (int w = 0; w < NW; w++) s += qP[w][o][r][c];
    if (o == 0) q[(size_t)(j0 + r) * DH + c] = s;
    else if (o == 1) kT[(size_t)c * SQ + (j0 + r)] = s;
    else v[(size_t)(j0 + r) * DH + c] = s;
  }
}

__global__ __launch_bounds__(NT) void fused_kernel(
    float* __restrict__ cur,
    const float* __restrict__ q, const float* __restrict__ kT,
    const float* __restrict__ v, const float4* __restrict__ VT4h,
    const float4* __restrict__ Wq4n, const float4* __restrict__ Wk4n,
    const float4* __restrict__ Wv4n,
    float* __restrict__ qn, float* __restrict__ kTn, float* __restrict__ vn,
    float* __restrict__ out, int flags) {
  __shared__ union SMemF {
    struct { float sL[NQ][W2]; float pL[NW][NQ][DH]; } a;
    float qP[NW][3][NQ][DH];
  } sm;
  __shared__ float qL[NQ][DH];
  __shared__ float dL[NQ][DH];
  __shared__ float yL[NQ][DE];

  int tid = threadIdx.x, lane = tid & 63, wv = tid >> 6;
  int j0 = swz_block(blockIdx.x) * NQ;

  if (tid < NQ * DH) ((float*)qL)[tid] = q[(size_t)j0 * DH + tid];
  __syncthreads();

  {
    int goff = wv * 64 + lane;
    if (goff < UW) {
      int g = j0 - CW + goff;
      bool valid = (g >= 0 && g < SQ);
      int gc = valid ? g : 0;
      float acc[NQ] = {0, 0, 0, 0};
#pragma unroll
      for (int d8 = 0; d8 < 8; d8++) {
        float kc[8];
#pragma unroll
        for (int u = 0; u < 8; u++) kc[u] = kT[(size_t)(d8 * 8 + u) * SQ + gc];
#pragma unroll
        for (int r = 0; r < NQ; r++) {
          float4 q0 = ((const float4*)qL[r])[2 * d8];
          float4 q1 = ((const float4*)qL[r])[2 * d8 + 1];
          acc[r] += q0.x * kc[0] + q0.y * kc[1] + q0.z * kc[2] + q0.w * kc[3] +
                    q1.x * kc[4] + q1.y * kc[5] + q1.z * kc[6] + q1.w * kc[7];
        }
      }
#pragma unroll
      for (int r = 0; r < NQ; r++) {
        int p = goff - r;
        if (p >= 0 && p < W2) sm.a.sL[r][p] = valid ? acc[r] * 0.125f : -INFINITY;
      }
    }
  }
  __syncthreads();

  if (wv < NQ) {
    int r = wv;
    float m = -INFINITY;
#pragma unroll
    for (int t = 0; t < 4; t++) m = fmaxf(m, sm.a.sL[r][lane + 64 * t]);
#pragma unroll
    for (int off = 32; off; off >>= 1) m = fmaxf(m, __shfl_xor(m, off));
    float ex[4], ss = 0;
#pragma unroll
    for (int t = 0; t < 4; t++) {
      ex[t] = __expf(sm.a.sL[r][lane + 64 * t] - m);
      ss += ex[t];
    }
#pragma unroll
    for (int off = 32; off; off >>= 1) ss += __shfl_xor(ss, off);
    float inv = 1.0f / ss;
#pragma unroll
    for (int t = 0; t < 4; t++) sm.a.sL[r][lane + 64 * t] = ex[t] * inv;
  }
  __syncthreads();

  {
    float dacc[NQ] = {0, 0, 0, 0};
    int gbeg = 33 * wv;
#pragma unroll
    for (int ch = 0; ch < 3; ch++) {
      float vc[11];
#pragma unroll
      for (int i = 0; i < 11; i++) {
        int goff = gbeg + ch * 11 + i;
        int g = j0 - CW + goff;
        int gc = g < 0 ? 0 : (g >= SQ ? SQ - 1 : g);
        vc[i] = v[(size_t)gc * DH + lane];
      }
#pragma unroll
      for (int i = 0; i < 11; i++) {
        int goff = gbeg + ch * 11 + i;
        bool act = goff < UW;
#pragma unroll
        for (int r = 0; r < NQ; r++) {
          int p = goff - r;
          float w = (act && p >= 0 && p < W2) ? sm.a.sL[r][p & 255] : 0.0f;
          dacc[r] += w * vc[i];
        }
      }
    }
#pragma unroll
    for (int r = 0; r < NQ; r++) sm.a.pL[wv][r][lane] = dacc[r];
  }
  __syncthreads();
  if (tid < NQ * DH) {
    int r = tid >> 6, c = tid & 63;
    float s = 0;
#pragma unroll
    for (int w = 0; w < NW; w++) s += sm.a.pL[w][r][c];
    dL[r][c] = s;
  }
  __syncthreads();

  float c8[8];
  {
    int e = tid;
    float cr[NQ];
#pragma unroll
    for (int r = 0; r < NQ; r++) cr[r] = cur[(size_t)(j0 + r) * DE + e];
    if (wv < NQ) {
      size_t jrow = (size_t)(j0 + wv) * DE;
#pragma unroll
      for (int t = 0; t < 8; t++) c8[t] = cur[jrow + lane + 64 * t];
    }
    float acc[NQ] = {0, 0, 0, 0};
#pragma unroll
    for (int c4 = 0; c4 < 16; c4++) {
      float4 wc4 = VT4h[c4 * 512 + e];
#pragma unroll
      for (int r = 0; r < NQ; r++) {
        float4 df = ((const float4*)dL[r])[c4];
        acc[r] += df.x * wc4.x + df.y * wc4.y + df.z * wc4.z + df.w * wc4.w;
      }
    }
#pragma unroll
    for (int r = 0; r < NQ; r++) yL[r][e] = cr[r] + acc[r];
  }
  __syncthreads();

  if (wv < NQ) {
    int r = wv;
    size_t jrow = (size_t)(j0 + r) * DE;
    float s = 0;
#pragma unroll
    for (int t = 0; t < 8; t++) s += yL[r][lane + 64 * t];
#pragma unroll
    for (int off = 32; off; off >>= 1) s += __shfl_xor(s, off);
    float inv_m1 = 512.0f / s;
    float y2[8], s2 = 0, s2q = 0;
#pragma unroll
    for (int t = 0; t < 8; t++) {
      y2[t] = yL[r][lane + 64 * t] * inv_m1;
      s2 += y2[t];
      s2q += y2[t] * y2[t];
    }
#pragma unroll
    for (int off = 32; off; off >>= 1) {
      s2 += __shfl_xor(s2, off);
      s2q += __shfl_xor(s2q, off);
    }
    float m2 = s2 * (1.0f / 512.0f);
    float var = (s2q - 512.0f * m2 * m2) * (1.0f / 511.0f);
    float isd = 1.0f / sqrtf(var);
#pragma unroll
    for (int t = 0; t < 8; t++) {
      int e = lane + 64 * t;
      float o = (y2[t] - m2) * isd + m2;
      float nc = c8[t] + o;
      cur[jrow + e] = nc;
      yL[r][e] = nc;
      if (flags & 1) out[jrow + e] = nc * (1.0f / NH);
    }
  }
  __syncthreads();

  if (flags & 2) {
    float aq[NQ] = {0, 0, 0, 0}, ak[NQ] = {0, 0, 0, 0}, av[NQ] = {0, 0, 0, 0};
    int e0 = wv * 64;
#pragma unroll
    for (int i4 = 0; i4 < 16; i4++) {
      int widx = (wv * 16 + i4) * 64 + lane;
      float4 wq4 = Wq4n[widx];
      float4 wk4 = Wk4n[widx];
      float4 wv4 = Wv4n[widx];
#pragma unroll
      for (int r = 0; r < NQ; r++) {
        float4 xr = ((const float4*)&yL[r][e0])[i4];
        aq[r] += xr.x * wq4.x + xr.y * wq4.y + xr.z * wq4.z + xr.w * wq4.w;
        ak[r] += xr.x * wk4.x + xr.y * wk4.y + xr.z * wk4.z + xr.w * wk4.w;
        av[r] += xr.x * wv4.x + xr.y * wv4.y + xr.z * wv4.z + xr.w * wv4.w;
      }
    }
#pragma unroll
    for (int r = 0; r < NQ; r++) {
      sm.qP[wv][0][r][lane] = aq[r];
      sm.qP[wv][1][r][lane] = ak[r];
      sm.qP[wv][2][r][lane] = av[r];
    }
    __syncthreads();
    for (int i = tid; i < 3 * NQ * DH; i += NT) {
      int o = i >> 8;
      int rem = i & 255;
      int r = rem >> 6, c = rem & 63;
      float s = 0;
#pragma unroll
      for (int w = 0; w < NW; w++) s += sm.qP[w][o][r][c];
      if (o == 0) qn[(size_t)(j0 + r) * DH + c] = s;
      else if (o == 1) kTn[(size_t)c * SQ + (j0 + r)] = s;
      else vn[(size_t)(j0 + r) * DH + c] = s;
    }
  }
}

extern "C" void kernel_launch(void* const* d_in, const int* in_sizes, int n_in,
                              void* d_out, int out_size, void* d_ws, size_t ws_size,
                              hipStream_t stream) {
  const float* x   = (const float*)d_in[0];
  const float* Wq  = (const float*)d_in[1];
  const float* Wk  = (const float*)d_in[2];
  const float* Wvd = (const float*)d_in[3];
  const float* Wvu = (const float*)d_in[4];
  float* out = (float*)d_out;

  float* ws  = (float*)d_ws;
  float* cur = ws;                    // SQ*DE (fallback only)
  float* qA  = cur + SQ * DE;         // SQ*DH each; k in kT layout [DH][SQ]
  float* kA  = qA + SQ * DH;
  float* vA  = kA + SQ * DH;
  float* qB  = vA + SQ * DH;
  float* kB  = qB + SQ * DH;
  float* vB  = kB + SQ * DH;
  float* WTq = vB + SQ * DH;          // NH*DE*DH each (packed float4 layout)
  float* WTk = WTq + NH * DE * DH;
  float* WTv = WTk + NH * DE * DH;
  float* VT  = WTv + NH * DE * DH;    // NH*DH*DE (packed float4 layout)

  prep_kernel<<<NH * DE * DH / 256, 256, 0, stream>>>(Wq, Wk, Wvd, Wvu,
                                                      WTq, WTk, WTv, VT);

  // Cooperative persistent path if 2 blocks/CU residency is confirmed.
  bool done = false;
  int maxB = 0;
  if (hipOccupancyMaxActiveBlocksPerMultiprocessor(&maxB, persist_kernel, NT,
                                                   0) == hipSuccess &&
      maxB >= 2) {
    const float4* WTq4 = (const float4*)WTq;
    const float4* WTk4 = (const float4*)WTk;
    const float4* WTv4 = (const float4*)WTv;
    const float4* VT4  = (const float4*)VT;
    void* args[] = {(void*)&x, (void*)&WTq4, (void*)&WTk4, (void*)&WTv4,
                    (void*)&VT4, (void*)&kA, (void*)&vA, (void*)&kB,
                    (void*)&vB, (void*)&out};
    if (hipLaunchCooperativeKernel((const void*)persist_kernel, dim3(NB),
                                   dim3(NT), args, 0, stream) == hipSuccess)
      done = true;
  }

  if (!done) {
    qkv0_kernel<<<NB, NT, 0, stream>>>(
        x, (const float4*)WTq, (const float4*)WTk, (const float4*)WTv,
        cur, qA, kA, vA);
    for (int h = 0; h < NH; h++) {
      const float* qi = (h & 1) ? qB : qA;
      const float* ki = (h & 1) ? kB : kA;
      const float* vi = (h & 1) ? vB : vA;
      float* qo = (h & 1) ? qA : qB;
      float* ko = (h & 1) ? kA : kB;
      float* vo = (h & 1) ? vA : vB;
      const size_t won = (size_t)(h + 1 < NH ? h + 1 : 0) * DE * DH / 4;
      int flags = (h == NH - 1 ? 1 : 0) | (h < NH - 1 ? 2 : 0);
      fused_kernel<<<NB, NT, 0, stream>>>(
          cur, qi, ki, vi, (const float4*)VT + (size_t)h * DH * DE / 4,
          (const float4*)WTq + won, (const float4*)WTk + won,
          (const float4*)WTv + won, qo, ko, vo, out, flags);
    }
  }
}

// Round 8
// 266.349 us; speedup vs baseline: 1.4516x; 1.1851x over previous
//
#include <hip/hip_runtime.h>
#include <math.h>

#define SQ 2048      // seq len
#define DE 512       // d_embedding
#define DH 64        // d_head
#define CW 128       // half-window
#define W2 256       // window width
#define NH 8         // heads
#define NQ 4         // queries per block
#define UW (W2 + NQ - 1)  // union window width = 259
#define NT 512       // threads per block
#define NW 8         // waves per block
#define NB (SQ / NQ) // 512 blocks = 2 per CU

typedef _Float16 f16x2 __attribute__((ext_vector_type(2)));

// v_dot2_f32_f16: acc += a.lo*b.lo + a.hi*b.hi (fp32 accumulate)
__device__ __forceinline__ float dot2(unsigned a, unsigned b, float c) {
  union { unsigned u; f16x2 h; } ua, ub;
  ua.u = a; ub.u = b;
  return __builtin_amdgcn_fdot2(ua.h, ub.h, c, false);
}

__device__ __forceinline__ unsigned pack2(float lo, float hi) {
  union { unsigned u; _Float16 h[2]; } x;
  x.h[0] = (_Float16)lo; x.h[1] = (_Float16)hi;
  return x.u;
}

// XCD-chunk swizzle (bijective for 512 blocks, 8 XCDs).
__device__ __forceinline__ int swz_block(int b) {
  return ((b & 7) << 6) | (b >> 3);
}

// prep: f16-packed weight layouts (uint4 = 8 halves).
// WH*[t], t=((h*8+wv)*8+i2)*64+lane: halves e=wv*64+i2*8+k (k=0..7), col c=lane.
// VH[t],  t=(h*8+c8)*512+e:          halves c=c8*8+k, row e.
__global__ __launch_bounds__(256) void prep_kernel(
    const float* __restrict__ Wq, const float* __restrict__ Wk,
    const float* __restrict__ Wvd, const float* __restrict__ Wvu,
    uint4* __restrict__ WHq, uint4* __restrict__ WHk,
    uint4* __restrict__ WHv, uint4* __restrict__ VH) {
  int t = blockIdx.x * 256 + threadIdx.x;
  if (t >= NH * DE * DH / 8) return;
  {
    int lane = t & 63, i2 = (t >> 6) & 7, wvq = (t >> 9) & 7, h = t >> 12;
    int e = wvq * 64 + i2 * 8;
    size_t s = ((size_t)(h * DH + lane)) * DE + e;
    WHq[t] = make_uint4(pack2(Wq[s], Wq[s + 1]), pack2(Wq[s + 2], Wq[s + 3]),
                        pack2(Wq[s + 4], Wq[s + 5]), pack2(Wq[s + 6], Wq[s + 7]));
    WHk[t] = make_uint4(pack2(Wk[s], Wk[s + 1]), pack2(Wk[s + 2], Wk[s + 3]),
                        pack2(Wk[s + 4], Wk[s + 5]), pack2(Wk[s + 6], Wk[s + 7]));
    WHv[t] = make_uint4(pack2(Wvd[s], Wvd[s + 1]), pack2(Wvd[s + 2], Wvd[s + 3]),
                        pack2(Wvd[s + 4], Wvd[s + 5]), pack2(Wvd[s + 6], Wvd[s + 7]));
  }
  {
    int e = t & 511, c8 = (t >> 9) & 7, h = t >> 12;
    size_t s = ((size_t)h * DE + e) * DH + c8 * 8;
    VH[t] = make_uint4(pack2(Wvu[s], Wvu[s + 1]), pack2(Wvu[s + 2], Wvu[s + 3]),
                       pack2(Wvu[s + 4], Wvu[s + 5]), pack2(Wvu[s + 6], Wvu[s + 7]));
  }
}

// qkv0: x -> cur copy + q/kT/v for head 0 (f16 dot2 path)
__global__ __launch_bounds__(NT) void qkv0_kernel(
    const float* __restrict__ x, const uint4* __restrict__ WHq,
    const uint4* __restrict__ WHk, const uint4* __restrict__ WHv,
    float* __restrict__ cur, float* __restrict__ q, float* __restrict__ kT,
    float* __restrict__ v) {
  __shared__ _Float16 xH[NQ][DE];       // 4 KB
  __shared__ float qP[NW][3][NQ][DH];   // 24 KB
  int tid = threadIdx.x, lane = tid & 63, wv = tid >> 6;
  int j0 = swz_block(blockIdx.x) * NQ;

  float4 xv = ((const float4*)(x + (size_t)j0 * DE))[tid];
  ((float4*)(cur + (size_t)j0 * DE))[tid] = xv;
  {
    _Float16* xh = &((_Float16*)xH)[tid * 4];
    xh[0] = (_Float16)xv.x; xh[1] = (_Float16)xv.y;
    xh[2] = (_Float16)xv.z; xh[3] = (_Float16)xv.w;
  }
  __syncthreads();

  float aq[NQ] = {0, 0, 0, 0}, ak[NQ] = {0, 0, 0, 0}, av[NQ] = {0, 0, 0, 0};
  int e0 = wv * 64;
#pragma unroll
  for (int i2 = 0; i2 < 8; i2++) {
    int widx = (wv * 8 + i2) * 64 + lane;
    uint4 wq = WHq[widx];
    uint4 wk = WHk[widx];
    uint4 wvv = WHv[widx];
#pragma unroll
    for (int r = 0; r < NQ; r++) {
      uint4 xr = *(const uint4*)&xH[r][e0 + i2 * 8];  // wave-uniform broadcast
      aq[r] = dot2(xr.x, wq.x, aq[r]);  aq[r] = dot2(xr.y, wq.y, aq[r]);
      aq[r] = dot2(xr.z, wq.z, aq[r]);  aq[r] = dot2(xr.w, wq.w, aq[r]);
      ak[r] = dot2(xr.x, wk.x, ak[r]);  ak[r] = dot2(xr.y, wk.y, ak[r]);
      ak[r] = dot2(xr.z, wk.z, ak[r]);  ak[r] = dot2(xr.w, wk.w, ak[r]);
      av[r] = dot2(xr.x, wvv.x, av[r]); av[r] = dot2(xr.y, wvv.y, av[r]);
      av[r] = dot2(xr.z, wvv.z, av[r]); av[r] = dot2(xr.w, wvv.w, av[r]);
    }
  }
#pragma unroll
  for (int r = 0; r < NQ; r++) {
    qP[wv][0][r][lane] = aq[r];
    qP[wv][1][r][lane] = ak[r];
    qP[wv][2][r][lane] = av[r];
  }
  __syncthreads();
  for (int i = tid; i < 3 * NQ * DH; i += NT) {
    int o = i >> 8;
    int rem = i & 255;
    int r = rem >> 6, c = rem & 63;
    float s = 0;
#pragma unroll
    for (int w = 0; w < NW; w++) s += qP[w][o][r][c];
    if (o == 0) q[(size_t)(j0 + r) * DH + c] = s;
    else if (o == 1) kT[(size_t)c * SQ + (j0 + r)] = s;
    else v[(size_t)(j0 + r) * DH + c] = s;
  }
}

// fused: attn(head h) [+ qkv(head h+1)], f16 dot2 on QKV & upproj weights.
// flags bit0: last head -> out = cur/8 ; bit1: compute next-head qkv
__global__ __launch_bounds__(NT) void fused_kernel(
    float* __restrict__ cur,
    const float* __restrict__ q, const float* __restrict__ kT,
    const float* __restrict__ v, const uint4* __restrict__ VH4h,
    const uint4* __restrict__ WHqn, const uint4* __restrict__ WHkn,
    const uint4* __restrict__ WHvn,
    float* __restrict__ qn, float* __restrict__ kTn, float* __restrict__ vn,
    float* __restrict__ out, int flags) {
  // qP (24KB, live only in P7) overlays sL+pL (12KB, dead by then).
  __shared__ union SMem {
    struct { float sL[NQ][W2]; float pL[NW][NQ][DH]; } a;
    float qP[NW][3][NQ][DH];
  } sm;
  __shared__ float qL[NQ][DH];       // 1 KB
  __shared__ _Float16 dH[NQ][DH];    // 512 B
  __shared__ float yL[NQ][DE];       // 8 KB
  __shared__ _Float16 yH[NQ][DE];    // 4 KB

  int tid = threadIdx.x, lane = tid & 63, wv = tid >> 6;
  int j0 = swz_block(blockIdx.x) * NQ;

  // P0: stage q rows
  if (tid < NQ * DH) ((float*)qL)[tid] = q[(size_t)j0 * DH + tid];
  __syncthreads();

  // P1: scores (fp32 path, unchanged)
  {
    int goff = wv * 64 + lane;
    if (goff < UW) {
      int g = j0 - CW + goff;
      bool valid = (g >= 0 && g < SQ);
      int gc = valid ? g : 0;
      float acc[NQ] = {0, 0, 0, 0};
#pragma unroll
      for (int d8 = 0; d8 < 8; d8++) {
        float kc[8];
#pragma unroll
        for (int u = 0; u < 8; u++) kc[u] = kT[(size_t)(d8 * 8 + u) * SQ + gc];
#pragma unroll
        for (int r = 0; r < NQ; r++) {
          float4 q0 = ((const float4*)qL[r])[2 * d8];
          float4 q1 = ((const float4*)qL[r])[2 * d8 + 1];
          acc[r] += q0.x * kc[0] + q0.y * kc[1] + q0.z * kc[2] + q0.w * kc[3] +
                    q1.x * kc[4] + q1.y * kc[5] + q1.z * kc[6] + q1.w * kc[7];
        }
      }
#pragma unroll
      for (int r = 0; r < NQ; r++) {
        int p = goff - r;
        if (p >= 0 && p < W2) sm.a.sL[r][p] = valid ? acc[r] * 0.125f : -INFINITY;
      }
    }
  }
  __syncthreads();

  // P2: softmax, wave per row
  if (wv < NQ) {
    int r = wv;
    float m = -INFINITY;
#pragma unroll
    for (int t = 0; t < 4; t++) m = fmaxf(m, sm.a.sL[r][lane + 64 * t]);
#pragma unroll
    for (int off = 32; off; off >>= 1) m = fmaxf(m, __shfl_xor(m, off));
    float ex[4], ss = 0;
#pragma unroll
    for (int t = 0; t < 4; t++) {
      ex[t] = __expf(sm.a.sL[r][lane + 64 * t] - m);
      ss += ex[t];
    }
#pragma unroll
    for (int off = 32; off; off >>= 1) ss += __shfl_xor(ss, off);
    float inv = 1.0f / ss;
#pragma unroll
    for (int t = 0; t < 4; t++) sm.a.sL[r][lane + 64 * t] = ex[t] * inv;
  }
  __syncthreads();

  // P3: PV, 3 chunks of 11 (fp32 path, unchanged)
  {
    float dacc[NQ] = {0, 0, 0, 0};
    int gbeg = 33 * wv;
#pragma unroll
    for (int ch = 0; ch < 3; ch++) {
      float vc[11];
#pragma unroll
      for (int i = 0; i < 11; i++) {
        int goff = gbeg + ch * 11 + i;
        int g = j0 - CW + goff;
        int gc = g < 0 ? 0 : (g >= SQ ? SQ - 1 : g);
        vc[i] = v[(size_t)gc * DH + lane];
      }
#pragma unroll
      for (int i = 0; i < 11; i++) {
        int goff = gbeg + ch * 11 + i;
        bool act = goff < UW;
#pragma unroll
        for (int r = 0; r < NQ; r++) {
          int p = goff - r;
          float w = (act && p >= 0 && p < W2) ? sm.a.sL[r][p & 255] : 0.0f;
          dacc[r] += w * vc[i];
        }
      }
    }
#pragma unroll
    for (int r = 0; r < NQ; r++) sm.a.pL[wv][r][lane] = dacc[r];
  }
  __syncthreads();
  if (tid < NQ * DH) {
    int r = tid >> 6, c = tid & 63;
    float s = 0;
#pragma unroll
    for (int w = 0; w < NW; w++) s += sm.a.pL[w][r][c];
    dH[r][c] = (_Float16)s;
  }
  __syncthreads();

  // P5: upproj with f16 dot2 (VH loads are half the bytes of fp32 VT)
  float c8v[8];
  {
    int e = tid;
    float cr[NQ];
#pragma unroll
    for (int r = 0; r < NQ; r++) cr[r] = cur[(size_t)(j0 + r) * DE + e];
    if (wv < NQ) {
      size_t jrow = (size_t)(j0 + wv) * DE;
#pragma unroll
      for (int t = 0; t < 8; t++) c8v[t] = cur[jrow + lane + 64 * t];
    }
    float acc[NQ] = {0, 0, 0, 0};
#pragma unroll
    for (int c8 = 0; c8 < 8; c8++) {
      uint4 wc = VH4h[c8 * 512 + e];
#pragma unroll
      for (int r = 0; r < NQ; r++) {
        uint4 df = *(const uint4*)&dH[r][c8 * 8];  // wave-uniform broadcast
        acc[r] = dot2(df.x, wc.x, acc[r]);
        acc[r] = dot2(df.y, wc.y, acc[r]);
        acc[r] = dot2(df.z, wc.z, acc[r]);
        acc[r] = dot2(df.w, wc.w, acc[r]);
      }
    }
#pragma unroll
    for (int r = 0; r < NQ; r++) yL[r][e] = cr[r] + acc[r];
  }
  __syncthreads();

  // P6: renorm + residual; wave per row; also emits f16 copy for P7 dot2.
  if (wv < NQ) {
    int r = wv;
    size_t jrow = (size_t)(j0 + r) * DE;
    float s = 0;
#pragma unroll
    for (int t = 0; t < 8; t++) s += yL[r][lane + 64 * t];
#pragma unroll
    for (int off = 32; off; off >>= 1) s += __shfl_xor(s, off);
    float inv_m1 = 512.0f / s;
    float y2[8], s2 = 0, s2q = 0;
#pragma unroll
    for (int t = 0; t < 8; t++) {
      y2[t] = yL[r][lane + 64 * t] * inv_m1;
      s2 += y2[t];
      s2q += y2[t] * y2[t];
    }
#pragma unroll
    for (int off = 32; off; off >>= 1) {
      s2 += __shfl_xor(s2, off);
      s2q += __shfl_xor(s2q, off);
    }
    float m2 = s2 * (1.0f / 512.0f);
    float var = (s2q - 512.0f * m2 * m2) * (1.0f / 511.0f);
    float isd = 1.0f / sqrtf(var);
#pragma unroll
    for (int t = 0; t < 8; t++) {
      int e = lane + 64 * t;
      float o = (y2[t] - m2) * isd + m2;
      float nc = c8v[t] + o;
      cur[jrow + e] = nc;
      yH[r][e] = (_Float16)nc;
      if (flags & 1) out[jrow + e] = nc * (1.0f / NH);
    }
  }
  __syncthreads();

  // P7: next-head qkv with f16 dot2 weight loads; wave e-slice.
  if (flags & 2) {
    float aq[NQ] = {0, 0, 0, 0}, ak[NQ] = {0, 0, 0, 0}, av[NQ] = {0, 0, 0, 0};
    int e0 = wv * 64;
#pragma unroll
    for (int i2 = 0; i2 < 8; i2++) {
      int widx = (wv * 8 + i2) * 64 + lane;
      uint4 wq = WHqn[widx];
      uint4 wk = WHkn[widx];
      uint4 wvv = WHvn[widx];
#pragma unroll
      for (int r = 0; r < NQ; r++) {
        uint4 xr = *(const uint4*)&yH[r][e0 + i2 * 8];  // wave-uniform broadcast
        aq[r] = dot2(xr.x, wq.x, aq[r]);  aq[r] = dot2(xr.y, wq.y, aq[r]);
        aq[r] = dot2(xr.z, wq.z, aq[r]);  aq[r] = dot2(xr.w, wq.w, aq[r]);
        ak[r] = dot2(xr.x, wk.x, ak[r]);  ak[r] = dot2(xr.y, wk.y, ak[r]);
        ak[r] = dot2(xr.z, wk.z, ak[r]);  ak[r] = dot2(xr.w, wk.w, ak[r]);
        av[r] = dot2(xr.x, wvv.x, av[r]); av[r] = dot2(xr.y, wvv.y, av[r]);
        av[r] = dot2(xr.z, wvv.z, av[r]); av[r] = dot2(xr.w, wvv.w, av[r]);
      }
    }
#pragma unroll
    for (int r = 0; r < NQ; r++) {
      sm.qP[wv][0][r][lane] = aq[r];
      sm.qP[wv][1][r][lane] = ak[r];
      sm.qP[wv][2][r][lane] = av[r];
    }
    __syncthreads();
    for (int i = tid; i < 3 * NQ * DH; i += NT) {
      int o = i >> 8;
      int rem = i & 255;
      int r = rem >> 6, c = rem & 63;
      float s = 0;
#pragma unroll
      for (int w = 0; w < NW; w++) s += sm.qP[w][o][r][c];
      if (o == 0) qn[(size_t)(j0 + r) * DH + c] = s;
      else if (o == 1) kTn[(size_t)c * SQ + (j0 + r)] = s;
      else vn[(size_t)(j0 + r) * DH + c] = s;
    }
  }
}

extern "C" void kernel_launch(void* const* d_in, const int* in_sizes, int n_in,
                              void* d_out, int out_size, void* d_ws, size_t ws_size,
                              hipStream_t stream) {
  const float* x   = (const float*)d_in[0];
  const float* Wq  = (const float*)d_in[1];
  const float* Wk  = (const float*)d_in[2];
  const float* Wvd = (const float*)d_in[3];
  const float* Wvu = (const float*)d_in[4];
  float* out = (float*)d_out;

  float* ws  = (float*)d_ws;
  float* cur = ws;                    // SQ*DE
  float* qA  = cur + SQ * DE;         // SQ*DH each; k in kT layout [DH][SQ]
  float* kA  = qA + SQ * DH;
  float* vA  = kA + SQ * DH;
  float* qB  = vA + SQ * DH;
  float* kB  = qB + SQ * DH;
  float* vB  = kB + SQ * DH;
  // f16 packed weights: 4096 uint4 per head per matrix
  uint4* WHq = (uint4*)(vB + SQ * DH);
  uint4* WHk = WHq + NH * 4096;
  uint4* WHv = WHk + NH * 4096;
  uint4* VH  = WHv + NH * 4096;

  prep_kernel<<<NH * DE * DH / 8 / 256, 256, 0, stream>>>(Wq, Wk, Wvd, Wvu,
                                                          WHq, WHk, WHv, VH);
  qkv0_kernel<<<NB, NT, 0, stream>>>(x, WHq, WHk, WHv, cur, qA, kA, vA);

  for (int h = 0; h < NH; h++) {
    const float* qi = (h & 1) ? qB : qA;
    const float* ki = (h & 1) ? kB : kA;
    const float* vi = (h & 1) ? vB : vA;
    float* qo = (h & 1) ? qA : qB;
    float* ko = (h & 1) ? kA : kB;
    float* vo = (h & 1) ? vA : vB;
    const size_t won = (size_t)(h + 1 < NH ? h + 1 : 0) * 4096;
    int flags = (h == NH - 1 ? 1 : 0) | (h < NH - 1 ? 2 : 0);
    fused_kernel<<<NB, NT, 0, stream>>>(
        cur, qi, ki, vi, VH + (size_t)h * 4096,
        WHq + won, WHk + won, WHv + won, qo, ko, vo, out, flags);
  }
}

// Round 9
// 238.611 us; speedup vs baseline: 1.6204x; 1.1162x over previous
//
#include <hip/hip_runtime.h>
#include <math.h>

#define SQ 2048      // seq len
#define DE 512       // d_embedding
#define DH 64        // d_head
#define CW 128       // half-window
#define W2 256       // window width
#define NH 8         // heads
#define NQ 4         // queries per block
#define UW (W2 + NQ - 1)  // union window width = 259
#define NT 512       // threads per block
#define NW 8         // waves per block
#define NB (SQ / NQ) // 512 blocks = 2 per CU

typedef _Float16 f16x2 __attribute__((ext_vector_type(2)));

// v_dot2_f32_f16: acc += a.lo*b.lo + a.hi*b.hi (fp32 accumulate)
__device__ __forceinline__ float dot2(unsigned a, unsigned b, float c) {
  union { unsigned u; f16x2 h; } ua, ub;
  ua.u = a; ub.u = b;
  return __builtin_amdgcn_fdot2(ua.h, ub.h, c, false);
}

__device__ __forceinline__ unsigned pack2(float lo, float hi) {
  union { unsigned u; _Float16 h[2]; } x;
  x.h[0] = (_Float16)lo; x.h[1] = (_Float16)hi;
  return x.u;
}

__device__ __forceinline__ unsigned short f2h(float f) {
  union { unsigned short u; _Float16 h; } x;
  x.h = (_Float16)f;
  return x.u;
}

__device__ __forceinline__ float h2f(unsigned short u) {
  union { unsigned short u; _Float16 h; } x;
  x.u = u;
  return (float)x.h;
}

// XCD-chunk swizzle (bijective for 512 blocks, 8 XCDs).
__device__ __forceinline__ int swz_block(int b) {
  return ((b & 7) << 6) | (b >> 3);
}

// prep: f16-packed weight layouts (uint4 = 8 halves).
// WH*[t], t=((h*8+wv)*8+i2)*64+lane: halves e=wv*64+i2*8+k (k=0..7), col c=lane.
// VH[t],  t=(h*8+c8)*512+e:          halves c=c8*8+k, row e.
__global__ __launch_bounds__(256) void prep_kernel(
    const float* __restrict__ Wq, const float* __restrict__ Wk,
    const float* __restrict__ Wvd, const float* __restrict__ Wvu,
    uint4* __restrict__ WHq, uint4* __restrict__ WHk,
    uint4* __restrict__ WHv, uint4* __restrict__ VH) {
  int t = blockIdx.x * 256 + threadIdx.x;
  if (t >= NH * DE * DH / 8) return;
  {
    int lane = t & 63, i2 = (t >> 6) & 7, wvq = (t >> 9) & 7, h = t >> 12;
    int e = wvq * 64 + i2 * 8;
    size_t s = ((size_t)(h * DH + lane)) * DE + e;
    WHq[t] = make_uint4(pack2(Wq[s], Wq[s + 1]), pack2(Wq[s + 2], Wq[s + 3]),
                        pack2(Wq[s + 4], Wq[s + 5]), pack2(Wq[s + 6], Wq[s + 7]));
    WHk[t] = make_uint4(pack2(Wk[s], Wk[s + 1]), pack2(Wk[s + 2], Wk[s + 3]),
                        pack2(Wk[s + 4], Wk[s + 5]), pack2(Wk[s + 6], Wk[s + 7]));
    WHv[t] = make_uint4(pack2(Wvd[s], Wvd[s + 1]), pack2(Wvd[s + 2], Wvd[s + 3]),
                        pack2(Wvd[s + 4], Wvd[s + 5]), pack2(Wvd[s + 6], Wvd[s + 7]));
  }
  {
    int e = t & 511, c8 = (t >> 9) & 7, h = t >> 12;
    size_t s = ((size_t)h * DE + e) * DH + c8 * 8;
    VH[t] = make_uint4(pack2(Wvu[s], Wvu[s + 1]), pack2(Wvu[s + 2], Wvu[s + 3]),
                       pack2(Wvu[s + 4], Wvu[s + 5]), pack2(Wvu[s + 6], Wvu[s + 7]));
  }
}

// Shared write-out: q rows f16 [SQ][DH]; kT f16 PAIR-PACKED [DH/2][SQ] (uint =
// d=2k,2k+1 at one position); v f16 [SQ][DH].
__device__ __forceinline__ void write_qkv(int i, int j0, float s,
                                          unsigned short* qn, unsigned* kTn,
                                          unsigned short* vn) {
  int o = i >> 8;
  int rem = i & 255;
  int r = rem >> 6, c = rem & 63;
  if (o == 0) qn[(size_t)(j0 + r) * DH + c] = f2h(s);
  else if (o == 1)
    ((unsigned short*)kTn)[((((size_t)(c >> 1)) * SQ + (j0 + r)) << 1) | (c & 1)] = f2h(s);
  else vn[(size_t)(j0 + r) * DH + c] = f2h(s);
}

// qkv0: x -> cur copy + q/kT/v for head 0 (f16 dot2 path)
__global__ __launch_bounds__(NT) void qkv0_kernel(
    const float* __restrict__ x, const uint4* __restrict__ WHq,
    const uint4* __restrict__ WHk, const uint4* __restrict__ WHv,
    float* __restrict__ cur, unsigned short* __restrict__ q,
    unsigned* __restrict__ kT, unsigned short* __restrict__ v) {
  __shared__ _Float16 xH[NQ][DE];       // 4 KB
  __shared__ float qP[NW][3][NQ][DH];   // 24 KB
  int tid = threadIdx.x, lane = tid & 63, wv = tid >> 6;
  int j0 = swz_block(blockIdx.x) * NQ;

  float4 xv = ((const float4*)(x + (size_t)j0 * DE))[tid];
  ((float4*)(cur + (size_t)j0 * DE))[tid] = xv;
  {
    _Float16* xh = &((_Float16*)xH)[tid * 4];
    xh[0] = (_Float16)xv.x; xh[1] = (_Float16)xv.y;
    xh[2] = (_Float16)xv.z; xh[3] = (_Float16)xv.w;
  }
  __syncthreads();

  float aq[NQ] = {0, 0, 0, 0}, ak[NQ] = {0, 0, 0, 0}, av[NQ] = {0, 0, 0, 0};
  int e0 = wv * 64;
#pragma unroll
  for (int i2 = 0; i2 < 8; i2++) {
    int widx = (wv * 8 + i2) * 64 + lane;
    uint4 wq = WHq[widx];
    uint4 wk = WHk[widx];
    uint4 wvv = WHv[widx];
#pragma unroll
    for (int r = 0; r < NQ; r++) {
      uint4 xr = *(const uint4*)&xH[r][e0 + i2 * 8];  // wave-uniform broadcast
      aq[r] = dot2(xr.x, wq.x, aq[r]);  aq[r] = dot2(xr.y, wq.y, aq[r]);
      aq[r] = dot2(xr.z, wq.z, aq[r]);  aq[r] = dot2(xr.w, wq.w, aq[r]);
      ak[r] = dot2(xr.x, wk.x, ak[r]);  ak[r] = dot2(xr.y, wk.y, ak[r]);
      ak[r] = dot2(xr.z, wk.z, ak[r]);  ak[r] = dot2(xr.w, wk.w, ak[r]);
      av[r] = dot2(xr.x, wvv.x, av[r]); av[r] = dot2(xr.y, wvv.y, av[r]);
      av[r] = dot2(xr.z, wvv.z, av[r]); av[r] = dot2(xr.w, wvv.w, av[r]);
    }
  }
#pragma unroll
  for (int r = 0; r < NQ; r++) {
    qP[wv][0][r][lane] = aq[r];
    qP[wv][1][r][lane] = ak[r];
    qP[wv][2][r][lane] = av[r];
  }
  __syncthreads();
  for (int i = tid; i < 3 * NQ * DH; i += NT) {
    float s = 0;
#pragma unroll
    for (int w = 0; w < NW; w++)
      s += qP[w][i >> 8][(i & 255) >> 6][i & 63];
    write_qkv(i, j0, s, q, kT, v);
  }
}

// fused: attn(head h) [+ qkv(head h+1)]; f16 everywhere except fp32 state cur.
// flags bit0: last head -> out = cur/8 ; bit1: compute next-head qkv
__global__ __launch_bounds__(NT) void fused_kernel(
    float* __restrict__ cur,
    const unsigned short* __restrict__ qH, const unsigned* __restrict__ kTp,
    const unsigned short* __restrict__ vH, const uint4* __restrict__ VH4h,
    const uint4* __restrict__ WHqn, const uint4* __restrict__ WHkn,
    const uint4* __restrict__ WHvn,
    unsigned short* __restrict__ qn, unsigned* __restrict__ kTn,
    unsigned short* __restrict__ vn,
    float* __restrict__ out, int flags) {
  // qP (24KB, live only in P7) overlays sL+pL (12KB, dead by then).
  __shared__ union SMem {
    struct { float sL[NQ][W2]; float pL[NW][NQ][DH]; } a;
    float qP[NW][3][NQ][DH];
  } sm;
  __shared__ _Float16 dH[NQ][DH];    // 512 B
  __shared__ float yL[NQ][DE];       // 8 KB
  __shared__ _Float16 yH[NQ][DE];    // 4 KB

  int tid = threadIdx.x, lane = tid & 63, wv = tid >> 6;
  int j0 = swz_block(blockIdx.x) * NQ;

  // P1: scores. q read directly from global (wave-uniform uint4 = 8 halves,
  // L2-warm) -- P0 staging phase + barrier deleted. kT pair-packed -> dot2.
  {
    int goff = wv * 64 + lane;
    if (goff < UW) {
      int g = j0 - CW + goff;
      bool valid = (g >= 0 && g < SQ);
      int gc = valid ? g : 0;
      float acc[NQ] = {0, 0, 0, 0};
#pragma unroll
      for (int d8 = 0; d8 < 8; d8++) {
        unsigned kc[4];
#pragma unroll
        for (int u = 0; u < 4; u++) kc[u] = kTp[(size_t)(d8 * 4 + u) * SQ + gc];
#pragma unroll
        for (int r = 0; r < NQ; r++) {
          uint4 qp = *(const uint4*)&qH[(size_t)(j0 + r) * DH + d8 * 8];
          acc[r] = dot2(qp.x, kc[0], acc[r]);
          acc[r] = dot2(qp.y, kc[1], acc[r]);
          acc[r] = dot2(qp.z, kc[2], acc[r]);
          acc[r] = dot2(qp.w, kc[3], acc[r]);
        }
      }
#pragma unroll
      for (int r = 0; r < NQ; r++) {
        int p = goff - r;
        if (p >= 0 && p < W2) sm.a.sL[r][p] = valid ? acc[r] * 0.125f : -INFINITY;
      }
    }
  }
  __syncthreads();

  // P2: softmax, wave per row
  if (wv < NQ) {
    int r = wv;
    float m = -INFINITY;
#pragma unroll
    for (int t = 0; t < 4; t++) m = fmaxf(m, sm.a.sL[r][lane + 64 * t]);
#pragma unroll
    for (int off = 32; off; off >>= 1) m = fmaxf(m, __shfl_xor(m, off));
    float ex[4], ss = 0;
#pragma unroll
    for (int t = 0; t < 4; t++) {
      ex[t] = __expf(sm.a.sL[r][lane + 64 * t] - m);
      ss += ex[t];
    }
#pragma unroll
    for (int off = 32; off; off >>= 1) ss += __shfl_xor(ss, off);
    float inv = 1.0f / ss;
#pragma unroll
    for (int t = 0; t < 4; t++) sm.a.sL[r][lane + 64 * t] = ex[t] * inv;
  }
  __syncthreads();

  // P3: PV, 3 chunks of 11; v is f16 (half the bytes), cvt on load.
  {
    float dacc[NQ] = {0, 0, 0, 0};
    int gbeg = 33 * wv;
#pragma unroll
    for (int ch = 0; ch < 3; ch++) {
      float vc[11];
#pragma unroll
      for (int i = 0; i < 11; i++) {
        int goff = gbeg + ch * 11 + i;
        int g = j0 - CW + goff;
        int gc = g < 0 ? 0 : (g >= SQ ? SQ - 1 : g);
        vc[i] = h2f(vH[(size_t)gc * DH + lane]);
      }
#pragma unroll
      for (int i = 0; i < 11; i++) {
        int goff = gbeg + ch * 11 + i;
        bool act = goff < UW;
#pragma unroll
        for (int r = 0; r < NQ; r++) {
          int p = goff - r;
          float w = (act && p >= 0 && p < W2) ? sm.a.sL[r][p & 255] : 0.0f;
          dacc[r] += w * vc[i];
        }
      }
    }
#pragma unroll
    for (int r = 0; r < NQ; r++) sm.a.pL[wv][r][lane] = dacc[r];
  }
  __syncthreads();
  if (tid < NQ * DH) {
    int r = tid >> 6, c = tid & 63;
    float s = 0;
#pragma unroll
    for (int w = 0; w < NW; w++) s += sm.a.pL[w][r][c];
    dH[r][c] = (_Float16)s;
  }
  __syncthreads();

  // P5: upproj with f16 dot2
  float c8v[8];
  {
    int e = tid;
    float cr[NQ];
#pragma unroll
    for (int r = 0; r < NQ; r++) cr[r] = cur[(size_t)(j0 + r) * DE + e];
    if (wv < NQ) {
      size_t jrow = (size_t)(j0 + wv) * DE;
#pragma unroll
      for (int t = 0; t < 8; t++) c8v[t] = cur[jrow + lane + 64 * t];
    }
    float acc[NQ] = {0, 0, 0, 0};
#pragma unroll
    for (int c8 = 0; c8 < 8; c8++) {
      uint4 wc = VH4h[c8 * 512 + e];
#pragma unroll
      for (int r = 0; r < NQ; r++) {
        uint4 df = *(const uint4*)&dH[r][c8 * 8];  // wave-uniform broadcast
        acc[r] = dot2(df.x, wc.x, acc[r]);
        acc[r] = dot2(df.y, wc.y, acc[r]);
        acc[r] = dot2(df.z, wc.z, acc[r]);
        acc[r] = dot2(df.w, wc.w, acc[r]);
      }
    }
#pragma unroll
    for (int r = 0; r < NQ; r++) yL[r][e] = cr[r] + acc[r];
  }
  __syncthreads();

  // P6: renorm + residual; wave per row; emits f16 copy for P7 dot2.
  if (wv < NQ) {
    int r = wv;
    size_t jrow = (size_t)(j0 + r) * DE;
    float s = 0;
#pragma unroll
    for (int t = 0; t < 8; t++) s += yL[r][lane + 64 * t];
#pragma unroll
    for (int off = 32; off; off >>= 1) s += __shfl_xor(s, off);
    float inv_m1 = 512.0f / s;
    float y2[8], s2 = 0, s2q = 0;
#pragma unroll
    for (int t = 0; t < 8; t++) {
      y2[t] = yL[r][lane + 64 * t] * inv_m1;
      s2 += y2[t];
      s2q += y2[t] * y2[t];
    }
#pragma unroll
    for (int off = 32; off; off >>= 1) {
      s2 += __shfl_xor(s2, off);
      s2q += __shfl_xor(s2q, off);
    }
    float m2 = s2 * (1.0f / 512.0f);
    float var = (s2q - 512.0f * m2 * m2) * (1.0f / 511.0f);
    float isd = 1.0f / sqrtf(var);
#pragma unroll
    for (int t = 0; t < 8; t++) {
      int e = lane + 64 * t;
      float o = (y2[t] - m2) * isd + m2;
      float nc = c8v[t] + o;
      cur[jrow + e] = nc;
      yH[r][e] = (_Float16)nc;
      if (flags & 1) out[jrow + e] = nc * (1.0f / NH);
    }
  }
  __syncthreads();

  // P7: next-head qkv with f16 dot2 weight loads; wave e-slice.
  if (flags & 2) {
    float aq[NQ] = {0, 0, 0, 0}, ak[NQ] = {0, 0, 0, 0}, av[NQ] = {0, 0, 0, 0};
    int e0 = wv * 64;
#pragma unroll
    for (int i2 = 0; i2 < 8; i2++) {
      int widx = (wv * 8 + i2) * 64 + lane;
      uint4 wq = WHqn[widx];
      uint4 wk = WHkn[widx];
      uint4 wvv = WHvn[widx];
#pragma unroll
      for (int r = 0; r < NQ; r++) {
        uint4 xr = *(const uint4*)&yH[r][e0 + i2 * 8];  // wave-uniform broadcast
        aq[r] = dot2(xr.x, wq.x, aq[r]);  aq[r] = dot2(xr.y, wq.y, aq[r]);
        aq[r] = dot2(xr.z, wq.z, aq[r]);  aq[r] = dot2(xr.w, wq.w, aq[r]);
        ak[r] = dot2(xr.x, wk.x, ak[r]);  ak[r] = dot2(xr.y, wk.y, ak[r]);
        ak[r] = dot2(xr.z, wk.z, ak[r]);  ak[r] = dot2(xr.w, wk.w, ak[r]);
        av[r] = dot2(xr.x, wvv.x, av[r]); av[r] = dot2(xr.y, wvv.y, av[r]);
        av[r] = dot2(xr.z, wvv.z, av[r]); av[r] = dot2(xr.w, wvv.w, av[r]);
      }
    }
#pragma unroll
    for (int r = 0; r < NQ; r++) {
      sm.qP[wv][0][r][lane] = aq[r];
      sm.qP[wv][1][r][lane] = ak[r];
      sm.qP[wv][2][r][lane] = av[r];
    }
    __syncthreads();
    for (int i = tid; i < 3 * NQ * DH; i += NT) {
      float s = 0;
#pragma unroll
      for (int w = 0; w < NW; w++)
        s += sm.qP[w][i >> 8][(i & 255) >> 6][i & 63];
      write_qkv(i, j0, s, qn, kTn, vn);
    }
  }
}

extern "C" void kernel_launch(void* const* d_in, const int* in_sizes, int n_in,
                              void* d_out, int out_size, void* d_ws, size_t ws_size,
                              hipStream_t stream) {
  const float* x   = (const float*)d_in[0];
  const float* Wq  = (const float*)d_in[1];
  const float* Wk  = (const float*)d_in[2];
  const float* Wvd = (const float*)d_in[3];
  const float* Wvu = (const float*)d_in[4];
  float* out = (float*)d_out;

  float* ws = (float*)d_ws;
  float* cur = ws;                                   // SQ*DE fp32
  unsigned short* qA = (unsigned short*)(cur + SQ * DE);  // SQ*DH f16
  unsigned short* qB = qA + SQ * DH;
  unsigned* kA = (unsigned*)(qB + SQ * DH);          // (DH/2)*SQ pair-packed
  unsigned* kB = kA + (DH / 2) * SQ;
  unsigned short* vA = (unsigned short*)(kB + (DH / 2) * SQ);  // SQ*DH f16
  unsigned short* vB = vA + SQ * DH;
  // f16 packed weights: 4096 uint4 per head per matrix
  uint4* WHq = (uint4*)(vB + SQ * DH);
  uint4* WHk = WHq + NH * 4096;
  uint4* WHv = WHk + NH * 4096;
  uint4* VH  = WHv + NH * 4096;

  prep_kernel<<<NH * DE * DH / 8 / 256, 256, 0, stream>>>(Wq, Wk, Wvd, Wvu,
                                                          WHq, WHk, WHv, VH);
  qkv0_kernel<<<NB, NT, 0, stream>>>(x, WHq, WHk, WHv, cur, qA, kA, vA);

  for (int h = 0; h < NH; h++) {
    const unsigned short* qi = (h & 1) ? qB : qA;
    const unsigned* ki = (h & 1) ? kB : kA;
    const unsigned short* vi = (h & 1) ? vB : vA;
    unsigned short* qo = (h & 1) ? qA : qB;
    unsigned* ko = (h & 1) ? kA : kB;
    unsigned short* vo = (h & 1) ? vA : vB;
    const size_t won = (size_t)(h + 1 < NH ? h + 1 : 0) * 4096;
    int flags = (h == NH - 1 ? 1 : 0) | (h < NH - 1 ? 2 : 0);
    fused_kernel<<<NB, NT, 0, stream>>>(
        cur, qi, ki, vi, VH + (size_t)h * 4096,
        WHq + won, WHk + won, WHv + won, qo, ko, vo, out, flags);
  }
}